// Round 4
// baseline (783.779 us; speedup 1.0000x reference)
//
#include <hip/hip_runtime.h>
#include <cstdint>
#include <cstddef>

// Problem constants
#define BB 4
#define SS 4096
#define DD 256
#define PIW 0.5f
#define NROW (BB * SS)

typedef float          f32x4  __attribute__((ext_vector_type(4)));
typedef __bf16         bf16v8 __attribute__((ext_vector_type(8)));
typedef unsigned short u16v8  __attribute__((ext_vector_type(8)));
typedef unsigned short u16v4  __attribute__((ext_vector_type(4)));

__device__ __forceinline__ f32x4 mfma_bf16(u16v8 a, u16v8 b, f32x4 c) {
    return __builtin_amdgcn_mfma_f32_16x16x32_bf16(
        __builtin_bit_cast(bf16v8, a), __builtin_bit_cast(bf16v8, b), c, 0, 0, 0);
}

__device__ __forceinline__ unsigned short f2bf(float f) {
    unsigned u = __float_as_uint(f);
    u += 0x7FFFu + ((u >> 16) & 1u);           // RNE (inputs finite)
    return (unsigned short)(u >> 16);
}
__device__ __forceinline__ float bf2f(unsigned short h) {
    return __uint_as_float(((unsigned)h) << 16);
}
__device__ __forceinline__ unsigned fenc(float x) {
    unsigned u = __float_as_uint(x);
    return (u & 0x80000000u) ? ~u : (u | 0x80000000u);
}
__device__ __forceinline__ float fdec(unsigned e) {
    return __uint_as_float((e & 0x80000000u) ? (e ^ 0x80000000u) : ~e);
}

__device__ __forceinline__ void split8(float4 x0, float4 x1, u16v8* h, u16v8* l) {
    float xs[8] = {x0.x, x0.y, x0.z, x0.w, x1.x, x1.y, x1.z, x1.w};
    #pragma unroll
    for (int e = 0; e < 8; e++) {
        unsigned short hh = f2bf(xs[e]);
        (*h)[e] = hh;
        (*l)[e] = f2bf(xs[e] - bf2f(hh));
    }
}

// ---------------------------------------------------------------------------
// Projections via split-bf16 MFMA (3-term). C = A[16384,256] @ W[256,256].
// z=0: qh/ql (scaled 1/16). z=1: kh/kl. z=2: vt_blk bf16, block-tiled
// [b][s>>5][d][s&31] so pass-2 V staging is fully coalesced. Inits gmax.
// ---------------------------------------------------------------------------
#define FPAD 36

__global__ __launch_bounds__(256) void proj_mfma(
    const float* __restrict__ query, const float* __restrict__ key_, const float* __restrict__ value,
    const float* __restrict__ Wq, const float* __restrict__ Wk, const float* __restrict__ Wv,
    unsigned short* __restrict__ qh, unsigned short* __restrict__ ql,
    unsigned short* __restrict__ kh, unsigned short* __restrict__ kl,
    unsigned short* __restrict__ vt_blk, unsigned* __restrict__ gmax)
{
    const int z = blockIdx.z;
    const float* A = (z == 0) ? query : (z == 1) ? key_ : value;
    const float* W = (z == 0) ? Wq    : (z == 1) ? Wk   : Wv;
    if (z == 0 && blockIdx.x == 0 && blockIdx.y == 0 && threadIdx.x == 0)
        *gmax = 0x007FFFFFu;   // fenc(-inf)

    __shared__ float Af[128][FPAD];
    __shared__ float Wf[128][FPAD];

    const int tid = threadIdx.x;
    const int lane = tid & 63, w = tid >> 6;
    const int wr = (w >> 1) * 64, wc = (w & 1) * 64;
    const int m = lane & 15, qq = lane >> 4;
    const int rowBase = blockIdx.y * 128;    // flattened B*S
    const int colBase = blockIdx.x * 128;

    f32x4 acc[4][4];
    #pragma unroll
    for (int i = 0; i < 4; i++)
        #pragma unroll
        for (int j = 0; j < 4; j++)
            acc[i][j] = (f32x4){0.f, 0.f, 0.f, 0.f};

    for (int k0 = 0; k0 < DD; k0 += 32) {
        #pragma unroll
        for (int i = 0; i < 4; i++) {
            int c = tid + i * 256;
            int r = c >> 3, q8 = c & 7;
            *(float4*)&Af[r][q8 * 4] = *(const float4*)&A[(size_t)(rowBase + r) * DD + k0 + q8 * 4];
        }
        {
            int c = tid & 127, kk0 = (tid >> 7) * 16;
            #pragma unroll
            for (int kk = 0; kk < 16; kk++)
                Wf[c][kk0 + kk] = W[(size_t)(k0 + kk0 + kk) * DD + colBase + c];
        }
        __syncthreads();

        u16v8 ah[4], al[4], bh[4], bl[4];
        #pragma unroll
        for (int i = 0; i < 4; i++) {
            float4 x0 = *(const float4*)&Af[wr + i * 16 + m][qq * 8];
            float4 x1 = *(const float4*)&Af[wr + i * 16 + m][qq * 8 + 4];
            split8(x0, x1, &ah[i], &al[i]);
        }
        #pragma unroll
        for (int j = 0; j < 4; j++) {
            float4 x0 = *(const float4*)&Wf[wc + j * 16 + m][qq * 8];
            float4 x1 = *(const float4*)&Wf[wc + j * 16 + m][qq * 8 + 4];
            split8(x0, x1, &bh[j], &bl[j]);
        }
        #pragma unroll
        for (int i = 0; i < 4; i++)
            #pragma unroll
            for (int j = 0; j < 4; j++) {
                acc[i][j] = mfma_bf16(ah[i], bh[j], acc[i][j]);
                acc[i][j] = mfma_bf16(ah[i], bl[j], acc[i][j]);
                acc[i][j] = mfma_bf16(al[i], bh[j], acc[i][j]);
            }
        __syncthreads();
    }

    #pragma unroll
    for (int i = 0; i < 4; i++) {
        #pragma unroll
        for (int j = 0; j < 4; j++) {
            #pragma unroll
            for (int r = 0; r < 4; r++) {
                int gr  = rowBase + wr + i * 16 + qq * 4 + r;   // flattened B*S
                int col = colBase + wc + j * 16 + m;
                float v = acc[i][j][r];
                if (z == 2) {
                    int b2 = gr >> 12, s2 = gr & (SS - 1);
                    vt_blk[(((size_t)b2 * 128 + (s2 >> 5)) * DD + col) * 32 + (s2 & 31)] = f2bf(v);
                } else {
                    if (z == 0) v *= (1.0f / 16.0f);   // fold score scale into q
                    unsigned short hh = f2bf(v);
                    unsigned short ll = f2bf(v - bf2f(hh));
                    size_t idx = (size_t)gr * DD + col;
                    if (z == 0) { qh[idx] = hh; ql[idx] = ll; }
                    else        { kh[idx] = hh; kl[idx] = ll; }
                }
            }
        }
    }
}

// ---------------------------------------------------------------------------
// Pass 1: scores stats only (no score writes). Split-bf16 MFMA, 128x128 tile.
// Emits pmax/psum partials [32][NROW], exact diag scores dvec, gmax.
// K-chunk order (0,32,...,224) and term order (hh,hl,lh) MUST match pass 2.
// ---------------------------------------------------------------------------
#define SPAD 40

__global__ __launch_bounds__(256) void scores_stats(
    const unsigned short* __restrict__ qh, const unsigned short* __restrict__ ql,
    const unsigned short* __restrict__ kh, const unsigned short* __restrict__ kl,
    float* __restrict__ pmax, float* __restrict__ psum,
    float* __restrict__ dvec, unsigned* __restrict__ gmax)
{
    const int b = blockIdx.z;
    const size_t boff = (size_t)b * SS * DD;
    const unsigned short* Qh = qh + boff;
    const unsigned short* Ql = ql + boff;
    const unsigned short* Kh = kh + boff;
    const unsigned short* Kl = kl + boff;

    __shared__ unsigned short Ah[128][SPAD];
    __shared__ unsigned short Al[128][SPAD];
    __shared__ unsigned short Bh[128][SPAD];
    __shared__ unsigned short Bl[128][SPAD];
    __shared__ float smax[128][2];
    __shared__ float ssum[128][2];
    __shared__ float red[256];

    const int tid = threadIdx.x;
    const int lane = tid & 63, w = tid >> 6;
    const int wr = (w >> 1) * 64, wc = (w & 1) * 64;
    const int m = lane & 15, qq = lane >> 4;
    const int rowBase = blockIdx.y * 128;
    const int colBase = blockIdx.x * 128;

    f32x4 acc[4][4];
    #pragma unroll
    for (int i = 0; i < 4; i++)
        #pragma unroll
        for (int j = 0; j < 4; j++)
            acc[i][j] = (f32x4){0.f, 0.f, 0.f, 0.f};

    const int chunk = (tid & 3) * 8;
    const int srow  = tid >> 2;

    for (int k0 = 0; k0 < DD; k0 += 32) {
        #pragma unroll
        for (int i = 0; i < 2; i++) {
            int r = srow + i * 64;
            size_t ga = (size_t)(rowBase + r) * DD + k0 + chunk;
            size_t gb = (size_t)(colBase + r) * DD + k0 + chunk;
            *(u16v8*)&Ah[r][chunk] = *(const u16v8*)&Qh[ga];
            *(u16v8*)&Al[r][chunk] = *(const u16v8*)&Ql[ga];
            *(u16v8*)&Bh[r][chunk] = *(const u16v8*)&Kh[gb];
            *(u16v8*)&Bl[r][chunk] = *(const u16v8*)&Kl[gb];
        }
        __syncthreads();

        const int kb = qq * 8;
        u16v8 ah[4], al[4], bh[4], bl[4];
        #pragma unroll
        for (int i = 0; i < 4; i++) {
            ah[i] = *(const u16v8*)&Ah[wr + i * 16 + m][kb];
            al[i] = *(const u16v8*)&Al[wr + i * 16 + m][kb];
            bh[i] = *(const u16v8*)&Bh[wc + i * 16 + m][kb];
            bl[i] = *(const u16v8*)&Bl[wc + i * 16 + m][kb];
        }
        #pragma unroll
        for (int i = 0; i < 4; i++)
            #pragma unroll
            for (int j = 0; j < 4; j++) {
                acc[i][j] = mfma_bf16(ah[i], bh[j], acc[i][j]);
                acc[i][j] = mfma_bf16(ah[i], bl[j], acc[i][j]);
                acc[i][j] = mfma_bf16(al[i], bh[j], acc[i][j]);
            }
        __syncthreads();
    }

    // Exact raw diag scores (diagonal tiles only; waves with wr==wc hold them)
    if (blockIdx.x == blockIdx.y && wr == wc && (m >> 2) == qq) {
        #pragma unroll
        for (int i = 0; i < 4; i++)
            dvec[b * SS + rowBase + wr + i * 16 + m] = acc[i][i][m & 3];
    }

    // Per-row (max,sumexp) over this 128-col tile
    float vm_all = -INFINITY;
    #pragma unroll
    for (int i = 0; i < 4; i++) {
        #pragma unroll
        for (int r = 0; r < 4; r++) {
            float vj[4];
            float vm = -INFINITY;
            #pragma unroll
            for (int j = 0; j < 4; j++) {
                vj[j] = acc[i][j][r];
                vm = fmaxf(vm, vj[j]);
            }
            #pragma unroll
            for (int o = 1; o < 16; o <<= 1)
                vm = fmaxf(vm, __shfl_xor(vm, o));
            float vs = 0.f;
            #pragma unroll
            for (int j = 0; j < 4; j++)
                vs += __expf(vj[j] - vm);
            #pragma unroll
            for (int o = 1; o < 16; o <<= 1)
                vs += __shfl_xor(vs, o);
            vm_all = fmaxf(vm_all, vm);
            if (m == 0) {
                smax[wr + i * 16 + qq * 4 + r][w & 1] = vm;
                ssum[wr + i * 16 + qq * 4 + r][w & 1] = vs;
            }
        }
    }
    red[tid] = vm_all;
    __syncthreads();
    if (tid < 128) {
        float m0 = smax[tid][0], m1 = smax[tid][1];
        float M = fmaxf(m0, m1);
        float P = ssum[tid][0] * __expf(m0 - M) + ssum[tid][1] * __expf(m1 - M);
        size_t idx = (size_t)blockIdx.x * NROW + (b * SS + rowBase + tid);
        pmax[idx] = M;
        psum[idx] = P;
    }
    for (int s2 = 128; s2 > 0; s2 >>= 1) {
        if (tid < s2) red[tid] = fmaxf(red[tid], red[tid + s2]);
        __syncthreads();
    }
    if (tid == 0) atomicMax(gmax, fenc(red[0]));
}

// ---------------------------------------------------------------------------
// Combine partials per row (exact diag swap via dvec) -> (max, 1/sum).
// ---------------------------------------------------------------------------
__global__ __launch_bounds__(256) void combine_kernel(
    const float* __restrict__ pmax, const float* __restrict__ psum,
    const float* __restrict__ dvec, const unsigned* __restrict__ gmax,
    float* __restrict__ rmax, float* __restrict__ rinv)
{
    const int row = blockIdx.x * 256 + threadIdx.x;   // 0..NROW-1
    const int i = row & (SS - 1);
    const float bias = PIW * fdec(*gmax);
    const float d = dvec[row];

    float M = -INFINITY;
    #pragma unroll 8
    for (int t = 0; t < 32; t++) M = fmaxf(M, pmax[(size_t)t * NROW + row]);
    const float db = d + bias;
    const float Mrow = fmaxf(M, db);
    const int t0 = i >> 7;
    float S = 0.f;
    #pragma unroll 8
    for (int t = 0; t < 32; t++) {
        float pm = pmax[(size_t)t * NROW + row];
        float P  = psum[(size_t)t * NROW + row];
        if (t == t0) P -= __expf(d - pm);
        S += P * __expf(pm - Mrow);
    }
    S += __expf(db - Mrow);
    rmax[row] = Mrow;
    rinv[row] = 1.0f / S;
}

// ---------------------------------------------------------------------------
// Pass 2: recompute scores tile-by-tile, normalize, write fp32 weights to
// d_out, and accumulate O += P@V in registers. BM=32 rows/block, col-tiles
// of 128, 256 threads (4 waves). LDS: resident Q (h+l), union(K-tiles | V-tile),
// P round-trip buffer. Grid (SS/32, BB) = 512 blocks, 2 blocks/CU.
// ---------------------------------------------------------------------------
#define QPAD 264   // shorts: 256+8
#define KPAD 72    // shorts: 64+8
#define PPAD 136   // shorts: 128+8

__global__ __launch_bounds__(256) void weights_av(
    const unsigned short* __restrict__ qh, const unsigned short* __restrict__ ql,
    const unsigned short* __restrict__ kh, const unsigned short* __restrict__ kl,
    const unsigned short* __restrict__ vt_blk,
    const float* __restrict__ rmax, const float* __restrict__ rinv,
    const unsigned* __restrict__ gmax,
    float* __restrict__ attn, float* __restrict__ out)
{
    const int b = blockIdx.y;
    const int rowBase = blockIdx.x * 32;              // within batch

    __shared__ unsigned short Qh[32][QPAD];
    __shared__ unsigned short Ql[32][QPAD];
    __shared__ unsigned short Ubuf[256 * KPAD];       // KH|KL or VT
    __shared__ unsigned short P[32][PPAD];
    __shared__ float sM[32], sI[32];

    unsigned short* KH = Ubuf;                        // [128][KPAD]
    unsigned short* KL = Ubuf + 128 * KPAD;           // [128][KPAD]
    unsigned short* VT = Ubuf;                        // [256][KPAD]

    const int tid = threadIdx.x;
    const int lane = tid & 63, w = tid >> 6;
    const int m = lane & 15, qq = lane >> 4;
    const float bias = PIW * fdec(*gmax);

    // Resident Q staging (32 rows x 256 k, h+l)
    {
        int r = tid >> 3, c0 = (tid & 7) * 32;
        size_t qoff = ((size_t)(b * SS + rowBase + r)) * DD + c0;
        #pragma unroll
        for (int u = 0; u < 4; u++) {
            *(u16v8*)&Qh[r][c0 + u * 8] = *(const u16v8*)&qh[qoff + u * 8];
            *(u16v8*)&Ql[r][c0 + u * 8] = *(const u16v8*)&ql[qoff + u * 8];
        }
        if (tid < 32) {
            sM[tid] = rmax[b * SS + rowBase + tid];
            sI[tid] = rinv[b * SS + rowBase + tid];
        }
    }
    __syncthreads();

    f32x4 accO[2][4];
    #pragma unroll
    for (int i = 0; i < 2; i++)
        #pragma unroll
        for (int j = 0; j < 4; j++)
            accO[i][j] = (f32x4){0.f, 0.f, 0.f, 0.f};

    for (int ct = 0; ct < SS / 128; ct++) {
        const int colBase = ct * 128;

        // ---- Phase A: recompute S[32][128] (identical chain to pass 1) ----
        f32x4 accS[2][2];
        #pragma unroll
        for (int i = 0; i < 2; i++)
            #pragma unroll
            for (int j = 0; j < 2; j++)
                accS[i][j] = (f32x4){0.f, 0.f, 0.f, 0.f};

        for (int k0 = 0; k0 < DD; k0 += 64) {
            {
                int kr = tid >> 1, kc = (tid & 1) * 32;
                size_t koff = ((size_t)(b * SS + colBase + kr)) * DD + k0 + kc;
                #pragma unroll
                for (int u = 0; u < 4; u++) {
                    *(u16v8*)&KH[kr * KPAD + kc + u * 8] = *(const u16v8*)&kh[koff + u * 8];
                    *(u16v8*)&KL[kr * KPAD + kc + u * 8] = *(const u16v8*)&kl[koff + u * 8];
                }
            }
            __syncthreads();
            #pragma unroll
            for (int kk = 0; kk < 64; kk += 32) {
                u16v8 ah[2], al[2], bh[2], bl[2];
                #pragma unroll
                for (int i = 0; i < 2; i++) {
                    ah[i] = *(const u16v8*)&Qh[i * 16 + m][k0 + kk + qq * 8];
                    al[i] = *(const u16v8*)&Ql[i * 16 + m][k0 + kk + qq * 8];
                }
                #pragma unroll
                for (int j = 0; j < 2; j++) {
                    bh[j] = *(const u16v8*)&KH[(w * 32 + j * 16 + m) * KPAD + kk + qq * 8];
                    bl[j] = *(const u16v8*)&KL[(w * 32 + j * 16 + m) * KPAD + kk + qq * 8];
                }
                #pragma unroll
                for (int i = 0; i < 2; i++)
                    #pragma unroll
                    for (int j = 0; j < 2; j++) {
                        accS[i][j] = mfma_bf16(ah[i], bh[j], accS[i][j]);
                        accS[i][j] = mfma_bf16(ah[i], bl[j], accS[i][j]);
                        accS[i][j] = mfma_bf16(al[i], bh[j], accS[i][j]);
                    }
            }
            __syncthreads();
        }

        // ---- Phase B: normalize, write fp32 weights, P -> LDS (bf16) ----
        #pragma unroll
        for (int i = 0; i < 2; i++) {
            #pragma unroll
            for (int j = 0; j < 2; j++) {
                #pragma unroll
                for (int rr = 0; rr < 4; rr++) {
                    int lrow = i * 16 + qq * 4 + rr;
                    int lcol = w * 32 + j * 16 + m;
                    int grow = rowBase + lrow, gcol = colBase + lcol;
                    float s = accS[i][j][rr];
                    if (grow == gcol) s += bias;
                    float wv = __expf(s - sM[lrow]) * sI[lrow];
                    attn[((size_t)b * SS + grow) * SS + gcol] = wv;
                    P[lrow][lcol] = f2bf(wv);
                }
            }
        }
        __syncthreads();

        // ---- Phase C: O += P[32][128] @ V[128][256] (vT block-tiled) ----
        for (int kk2 = 0; kk2 < 128; kk2 += 64) {
            #pragma unroll
            for (int h = 0; h < 2; h++) {
                int sblk = ct * 4 + (kk2 >> 5) + h;
                const unsigned short* src = vt_blk + ((size_t)(b * 128 + sblk)) * DD * 32;
                #pragma unroll
                for (int u = 0; u < 4; u++)
                    *(u16v8*)&VT[tid * KPAD + h * 32 + u * 8] = *(const u16v8*)&src[tid * 32 + u * 8];
            }
            __syncthreads();
            #pragma unroll
            for (int kk3 = 0; kk3 < 64; kk3 += 32) {
                u16v8 af[2], bf[4];
                #pragma unroll
                for (int i = 0; i < 2; i++)
                    af[i] = *(const u16v8*)&P[i * 16 + m][kk2 + kk3 + qq * 8];
                #pragma unroll
                for (int j = 0; j < 4; j++)
                    bf[j] = *(const u16v8*)&VT[(w * 64 + j * 16 + m) * KPAD + kk3 + qq * 8];
                #pragma unroll
                for (int i = 0; i < 2; i++)
                    #pragma unroll
                    for (int j = 0; j < 4; j++)
                        accO[i][j] = mfma_bf16(af[i], bf[j], accO[i][j]);
            }
            __syncthreads();
        }
    }

    // ---- Epilogue: write O ----
    #pragma unroll
    for (int i = 0; i < 2; i++) {
        #pragma unroll
        for (int j = 0; j < 4; j++) {
            #pragma unroll
            for (int rr = 0; rr < 4; rr++) {
                int row = rowBase + i * 16 + qq * 4 + rr;
                int col = w * 64 + j * 16 + m;
                out[((size_t)b * SS + row) * DD + col] = accO[i][j][rr];
            }
        }
    }
}

extern "C" void kernel_launch(void* const* d_in, const int* in_sizes, int n_in,
                              void* d_out, int out_size, void* d_ws, size_t ws_size,
                              hipStream_t stream)
{
    const float* query = (const float*)d_in[0];
    const float* key_  = (const float*)d_in[1];
    const float* value = (const float*)d_in[2];
    const float* Wq    = (const float*)d_in[3];
    const float* Wk    = (const float*)d_in[4];
    const float* Wv    = (const float*)d_in[5];

    float* out  = (float*)d_out;                          // [B,S,D]
    float* attn = out + (size_t)BB * SS * DD;             // [B,S,S]

    const size_t E = (size_t)BB * SS * DD;                // 4.19M elements
    unsigned short* qh = (unsigned short*)d_ws;
    unsigned short* ql = qh + E;
    unsigned short* kh = ql + E;
    unsigned short* kl = kh + E;
    unsigned short* vt_blk = kl + E;                      // [B][S/32][D][32]
    float* pmax = (float*)(vt_blk + E);                   // [32][NROW]
    float* psum = pmax + (size_t)32 * NROW;
    float* dvec = psum + (size_t)32 * NROW;               // [NROW]
    float* rmax = dvec + NROW;
    float* rinv = rmax + NROW;
    unsigned* gmax = (unsigned*)(rinv + NROW);

    // 1) projections via split-bf16 MFMA (+ gmax init)
    proj_mfma<<<dim3(DD / 128, NROW / 128, 3), 256, 0, stream>>>(
        query, key_, value, Wq, Wk, Wv, qh, ql, kh, kl, vt_blk, gmax);
    // 2) score stats (no score materialization) + exact diag + gmax
    scores_stats<<<dim3(SS / 128, SS / 128, BB), 256, 0, stream>>>(
        qh, ql, kh, kl, pmax, psum, dvec, gmax);
    // 3) combine partials -> per-row (max, 1/sum) with exact biased-diag swap
    combine_kernel<<<dim3(NROW / 256), 256, 0, stream>>>(
        pmax, psum, dvec, gmax, rmax, rinv);
    // 4) recompute scores, write weights, fused P@V
    weights_av<<<dim3(SS / 32, BB), 256, 0, stream>>>(
        qh, ql, kh, kl, vt_blk, rmax, rinv, gmax, attn, out);
}

// Round 5
// 708.641 us; speedup vs baseline: 1.1060x; 1.1060x over previous
//
#include <hip/hip_runtime.h>
#include <cstdint>
#include <cstddef>

// Problem constants
#define BB 4
#define SS 4096
#define DD 256
#define PIW 0.5f
#define NROW (BB * SS)

typedef float          f32x4  __attribute__((ext_vector_type(4)));
typedef __bf16         bf16v8 __attribute__((ext_vector_type(8)));
typedef unsigned short u16v8  __attribute__((ext_vector_type(8)));
typedef unsigned short u16v4  __attribute__((ext_vector_type(4)));

__device__ __forceinline__ f32x4 mfma_bf16(u16v8 a, u16v8 b, f32x4 c) {
    return __builtin_amdgcn_mfma_f32_16x16x32_bf16(
        __builtin_bit_cast(bf16v8, a), __builtin_bit_cast(bf16v8, b), c, 0, 0, 0);
}

__device__ __forceinline__ unsigned short f2bf(float f) {
    unsigned u = __float_as_uint(f);
    u += 0x7FFFu + ((u >> 16) & 1u);           // RNE (inputs finite)
    return (unsigned short)(u >> 16);
}
__device__ __forceinline__ float bf2f(unsigned short h) {
    return __uint_as_float(((unsigned)h) << 16);
}
__device__ __forceinline__ unsigned fenc(float x) {
    unsigned u = __float_as_uint(x);
    return (u & 0x80000000u) ? ~u : (u | 0x80000000u);
}
__device__ __forceinline__ float fdec(unsigned e) {
    return __uint_as_float((e & 0x80000000u) ? (e ^ 0x80000000u) : ~e);
}

__device__ __forceinline__ void split8(float4 x0, float4 x1, u16v8* h, u16v8* l) {
    float xs[8] = {x0.x, x0.y, x0.z, x0.w, x1.x, x1.y, x1.z, x1.w};
    #pragma unroll
    for (int e = 0; e < 8; e++) {
        unsigned short hh = f2bf(xs[e]);
        (*h)[e] = hh;
        (*l)[e] = f2bf(xs[e] - bf2f(hh));
    }
}

// ---------------------------------------------------------------------------
// Projections via split-bf16 MFMA (3-term). C = A[16384,256] @ W[256,256].
// z=0: qh/ql (scaled 1/16). z=1: kh/kl. z=2: vT bf16 [b][d][s]. Inits gmax.
// ---------------------------------------------------------------------------
#define FPAD 36

__global__ __launch_bounds__(256) void proj_mfma(
    const float* __restrict__ query, const float* __restrict__ key_, const float* __restrict__ value,
    const float* __restrict__ Wq, const float* __restrict__ Wk, const float* __restrict__ Wv,
    unsigned short* __restrict__ qh, unsigned short* __restrict__ ql,
    unsigned short* __restrict__ kh, unsigned short* __restrict__ kl,
    unsigned short* __restrict__ vT, unsigned* __restrict__ gmax)
{
    const int z = blockIdx.z;
    const float* A = (z == 0) ? query : (z == 1) ? key_ : value;
    const float* W = (z == 0) ? Wq    : (z == 1) ? Wk   : Wv;
    if (z == 0 && blockIdx.x == 0 && blockIdx.y == 0 && threadIdx.x == 0)
        *gmax = 0x007FFFFFu;   // fenc(-inf)

    __shared__ float Af[128][FPAD];
    __shared__ float Wf[128][FPAD];

    const int tid = threadIdx.x;
    const int lane = tid & 63, w = tid >> 6;
    const int wr = (w >> 1) * 64, wc = (w & 1) * 64;
    const int m = lane & 15, qq = lane >> 4;
    const int rowBase = blockIdx.y * 128;    // flattened B*S
    const int colBase = blockIdx.x * 128;

    f32x4 acc[4][4];
    #pragma unroll
    for (int i = 0; i < 4; i++)
        #pragma unroll
        for (int j = 0; j < 4; j++)
            acc[i][j] = (f32x4){0.f, 0.f, 0.f, 0.f};

    for (int k0 = 0; k0 < DD; k0 += 32) {
        #pragma unroll
        for (int i = 0; i < 4; i++) {
            int c = tid + i * 256;
            int r = c >> 3, q8 = c & 7;
            *(float4*)&Af[r][q8 * 4] = *(const float4*)&A[(size_t)(rowBase + r) * DD + k0 + q8 * 4];
        }
        {
            int c = tid & 127, kk0 = (tid >> 7) * 16;
            #pragma unroll
            for (int kk = 0; kk < 16; kk++)
                Wf[c][kk0 + kk] = W[(size_t)(k0 + kk0 + kk) * DD + colBase + c];
        }
        __syncthreads();

        u16v8 ah[4], al[4], bh[4], bl[4];
        #pragma unroll
        for (int i = 0; i < 4; i++) {
            float4 x0 = *(const float4*)&Af[wr + i * 16 + m][qq * 8];
            float4 x1 = *(const float4*)&Af[wr + i * 16 + m][qq * 8 + 4];
            split8(x0, x1, &ah[i], &al[i]);
        }
        #pragma unroll
        for (int j = 0; j < 4; j++) {
            float4 x0 = *(const float4*)&Wf[wc + j * 16 + m][qq * 8];
            float4 x1 = *(const float4*)&Wf[wc + j * 16 + m][qq * 8 + 4];
            split8(x0, x1, &bh[j], &bl[j]);
        }
        #pragma unroll
        for (int i = 0; i < 4; i++)
            #pragma unroll
            for (int j = 0; j < 4; j++) {
                acc[i][j] = mfma_bf16(ah[i], bh[j], acc[i][j]);
                acc[i][j] = mfma_bf16(ah[i], bl[j], acc[i][j]);
                acc[i][j] = mfma_bf16(al[i], bh[j], acc[i][j]);
            }
        __syncthreads();
    }

    #pragma unroll
    for (int i = 0; i < 4; i++) {
        #pragma unroll
        for (int j = 0; j < 4; j++) {
            #pragma unroll
            for (int r = 0; r < 4; r++) {
                int gr  = rowBase + wr + i * 16 + qq * 4 + r;   // flattened B*S
                int col = colBase + wc + j * 16 + m;
                float v = acc[i][j][r];
                if (z == 2) {
                    int b2 = gr >> 12, s2 = gr & (SS - 1);
                    vT[((size_t)b2 * DD + col) * SS + s2] = f2bf(v);
                } else {
                    if (z == 0) v *= (1.0f / 16.0f);   // fold score scale into q
                    unsigned short hh = f2bf(v);
                    unsigned short ll = f2bf(v - bf2f(hh));
                    size_t idx = (size_t)gr * DD + col;
                    if (z == 0) { qh[idx] = hh; ql[idx] = ll; }
                    else        { kh[idx] = hh; kl[idx] = ll; }
                }
            }
        }
    }
}

// ---------------------------------------------------------------------------
// Scores: raw = q@k^T (q pre-scaled) via split-bf16 MFMA (3 terms).
// Writes raw scores + transposed per-(128-col-tile, row) partials + gmax.
// ---------------------------------------------------------------------------
#define SPAD 40

__global__ __launch_bounds__(256) void scores_mfma(
    const unsigned short* __restrict__ qh, const unsigned short* __restrict__ ql,
    const unsigned short* __restrict__ kh, const unsigned short* __restrict__ kl,
    float* __restrict__ attn, float* __restrict__ pmax, float* __restrict__ psum,
    unsigned* __restrict__ gmax)
{
    const int b = blockIdx.z;
    const size_t boff = (size_t)b * SS * DD;
    const unsigned short* Qh = qh + boff;
    const unsigned short* Ql = ql + boff;
    const unsigned short* Kh = kh + boff;
    const unsigned short* Kl = kl + boff;
    float* C = attn + (size_t)b * SS * SS;

    __shared__ unsigned short Ah[128][SPAD];
    __shared__ unsigned short Al[128][SPAD];
    __shared__ unsigned short Bh[128][SPAD];
    __shared__ unsigned short Bl[128][SPAD];
    __shared__ float smax[128][2];
    __shared__ float ssum[128][2];
    __shared__ float red[256];

    const int tid = threadIdx.x;
    const int lane = tid & 63, w = tid >> 6;
    const int wr = (w >> 1) * 64, wc = (w & 1) * 64;
    const int m = lane & 15, qq = lane >> 4;
    const int rowBase = blockIdx.y * 128;
    const int colBase = blockIdx.x * 128;

    f32x4 acc[4][4];
    #pragma unroll
    for (int i = 0; i < 4; i++)
        #pragma unroll
        for (int j = 0; j < 4; j++)
            acc[i][j] = (f32x4){0.f, 0.f, 0.f, 0.f};

    const int chunk = (tid & 3) * 8;
    const int srow  = tid >> 2;

    for (int k0 = 0; k0 < DD; k0 += 32) {
        #pragma unroll
        for (int i = 0; i < 2; i++) {
            int r = srow + i * 64;
            size_t ga = (size_t)(rowBase + r) * DD + k0 + chunk;
            size_t gb = (size_t)(colBase + r) * DD + k0 + chunk;
            *(u16v8*)&Ah[r][chunk] = *(const u16v8*)&Qh[ga];
            *(u16v8*)&Al[r][chunk] = *(const u16v8*)&Ql[ga];
            *(u16v8*)&Bh[r][chunk] = *(const u16v8*)&Kh[gb];
            *(u16v8*)&Bl[r][chunk] = *(const u16v8*)&Kl[gb];
        }
        __syncthreads();

        const int kb = qq * 8;
        u16v8 ah[4], al[4], bh[4], bl[4];
        #pragma unroll
        for (int i = 0; i < 4; i++) {
            ah[i] = *(const u16v8*)&Ah[wr + i * 16 + m][kb];
            al[i] = *(const u16v8*)&Al[wr + i * 16 + m][kb];
            bh[i] = *(const u16v8*)&Bh[wc + i * 16 + m][kb];
            bl[i] = *(const u16v8*)&Bl[wc + i * 16 + m][kb];
        }
        #pragma unroll
        for (int i = 0; i < 4; i++)
            #pragma unroll
            for (int j = 0; j < 4; j++) {
                acc[i][j] = mfma_bf16(ah[i], bh[j], acc[i][j]);
                acc[i][j] = mfma_bf16(ah[i], bl[j], acc[i][j]);
                acc[i][j] = mfma_bf16(al[i], bh[j], acc[i][j]);
            }
        __syncthreads();
    }

    // Epilogue: write raw scores + per-row stats over this 128-col tile
    float vm_all = -INFINITY;
    #pragma unroll
    for (int i = 0; i < 4; i++) {
        #pragma unroll
        for (int r = 0; r < 4; r++) {
            int row = rowBase + wr + i * 16 + qq * 4 + r;
            float vj[4];
            float vm = -INFINITY;
            #pragma unroll
            for (int j = 0; j < 4; j++) {
                vj[j] = acc[i][j][r];
                C[(size_t)row * SS + colBase + wc + j * 16 + m] = vj[j];
                vm = fmaxf(vm, vj[j]);
            }
            #pragma unroll
            for (int o = 1; o < 16; o <<= 1)
                vm = fmaxf(vm, __shfl_xor(vm, o));
            float vs = 0.f;
            #pragma unroll
            for (int j = 0; j < 4; j++)
                vs += __expf(vj[j] - vm);
            #pragma unroll
            for (int o = 1; o < 16; o <<= 1)
                vs += __shfl_xor(vs, o);
            vm_all = fmaxf(vm_all, vm);
            if (m == 0) {
                smax[wr + i * 16 + qq * 4 + r][w & 1] = vm;
                ssum[wr + i * 16 + qq * 4 + r][w & 1] = vs;
            }
        }
    }
    red[tid] = vm_all;
    __syncthreads();
    if (tid < 128) {
        float m0 = smax[tid][0], m1 = smax[tid][1];
        float M = fmaxf(m0, m1);
        float P = ssum[tid][0] * __expf(m0 - M) + ssum[tid][1] * __expf(m1 - M);
        size_t idx = (size_t)blockIdx.x * NROW + (b * SS + rowBase + tid);
        pmax[idx] = M;
        psum[idx] = P;
    }
    for (int s2 = 128; s2 > 0; s2 >>= 1) {
        if (tid < s2) red[tid] = fmaxf(red[tid], red[tid + s2]);
        __syncthreads();
    }
    if (tid == 0) atomicMax(gmax, fenc(red[0]));
}

// ---------------------------------------------------------------------------
// Combine partials per row (exact diag swap from stored raw diag) ->
// per-row (max, 1/sum). Partials are [tile][row] for coalesced reads.
// ---------------------------------------------------------------------------
__global__ __launch_bounds__(256) void combine_kernel(
    const float* __restrict__ pmax, const float* __restrict__ psum,
    const float* __restrict__ attn, const unsigned* __restrict__ gmax,
    float* __restrict__ rmax, float* __restrict__ rinv)
{
    const int row = blockIdx.x * 256 + threadIdx.x;   // 0..NROW-1
    const int b = row >> 12, i = row & (SS - 1);
    const float bias = PIW * fdec(*gmax);
    const float d = attn[(size_t)b * SS * SS + (size_t)i * SS + i];

    float M = -INFINITY;
    #pragma unroll 8
    for (int t = 0; t < 32; t++) M = fmaxf(M, pmax[(size_t)t * NROW + row]);
    const float db = d + bias;
    const float Mrow = fmaxf(M, db);
    const int t0 = i >> 7;
    float S = 0.f;
    #pragma unroll 8
    for (int t = 0; t < 32; t++) {
        float pm = pmax[(size_t)t * NROW + row];
        float P  = psum[(size_t)t * NROW + row];
        if (t == t0) P -= __expf(d - pm);
        S += P * __expf(pm - Mrow);
    }
    S += __expf(db - Mrow);
    rmax[row] = Mrow;
    rinv[row] = 1.0f / S;
}

// ---------------------------------------------------------------------------
// Fused softmax + AV, double-buffered, one barrier per chunk.
// 512 threads (8 waves), BM=64 rows/block, BK=64 col-chunk, grid (64, BB).
// Reads raw scores, computes w = exp(s(+bias) - M)*inv, writes fp32 weights
// in place, stages bf16 P + V-tile (vT, L2-resident) to LDS, O in registers.
// Register prefetch of chunk ct+1 issued right after the barrier.
// ---------------------------------------------------------------------------
#define VPAD 72   // shorts: 64+8

__global__ __launch_bounds__(512) void av_fused2(
    float* __restrict__ attn, const unsigned short* __restrict__ vT,
    const float* __restrict__ rmax, const float* __restrict__ rinv,
    const unsigned* __restrict__ gmax, float* __restrict__ out)
{
    const int b = blockIdx.y;
    const int rowBase = blockIdx.x * 64;              // within batch
    float* A = attn + (size_t)b * SS * SS;
    const unsigned short* Bv = vT + (size_t)b * DD * SS;
    const float bias = PIW * fdec(*gmax);

    __shared__ unsigned short P[2][64][VPAD];         // 18.4 KB
    __shared__ unsigned short V[2][256][VPAD];        // 73.7 KB
    __shared__ float sM[64], sI[64];

    const int tid = threadIdx.x;
    const int lane = tid & 63, w = tid >> 6;          // 8 waves
    const int m = lane & 15, qq = lane >> 4;

    if (tid < 64) {
        sM[tid] = rmax[b * SS + rowBase + tid];
        sI[tid] = rinv[b * SS + rowBase + tid];
    }

    const int pr = tid >> 3, pc = (tid & 7) * 8;      // raw tile: row 0..63, col8
    const int vr = tid >> 1, vc = (tid & 1) * 32;     // V tile: d 0..255, col32
    const size_t rawRow = (size_t)(rowBase + pr) * SS;
    const size_t vRow   = (size_t)vr * SS;
    const int growDiag  = rowBase + pr;               // diagonal column for row pr

    // prologue: chunk 0 into registers
    float4 ra0 = *(const float4*)&A[rawRow + pc];
    float4 ra1 = *(const float4*)&A[rawRow + pc + 4];
    u16v8 rv[4];
    #pragma unroll
    for (int u = 0; u < 4; u++)
        rv[u] = *(const u16v8*)&Bv[vRow + vc + u * 8];
    __syncthreads();   // sM/sI visible

    f32x4 acc[4][2];
    #pragma unroll
    for (int i = 0; i < 4; i++)
        #pragma unroll
        for (int j = 0; j < 2; j++)
            acc[i][j] = (f32x4){0.f, 0.f, 0.f, 0.f};

    const float Mr = sM[pr], Ir = sI[pr];

    int cur = 0;
    for (int ct = 0; ct < SS / 64; ct++) {
        const int kc = ct * 64;
        // ---- stage chunk ct: softmax -> weights write + P bf16; V -> LDS ----
        {
            float xs[8] = {ra0.x, ra0.y, ra0.z, ra0.w, ra1.x, ra1.y, ra1.z, ra1.w};
            float wv[8];
            #pragma unroll
            for (int e = 0; e < 8; e++) {
                float s = xs[e] + ((kc + pc + e == growDiag) ? bias : 0.f);
                wv[e] = __expf(s - Mr) * Ir;
            }
            *(float4*)&A[rawRow + kc + pc]     = make_float4(wv[0], wv[1], wv[2], wv[3]);
            *(float4*)&A[rawRow + kc + pc + 4] = make_float4(wv[4], wv[5], wv[6], wv[7]);
            *(u16v4*)&P[cur][pr][pc]     = (u16v4){f2bf(wv[0]), f2bf(wv[1]), f2bf(wv[2]), f2bf(wv[3])};
            *(u16v4*)&P[cur][pr][pc + 4] = (u16v4){f2bf(wv[4]), f2bf(wv[5]), f2bf(wv[6]), f2bf(wv[7])};
            #pragma unroll
            for (int u = 0; u < 4; u++)
                *(u16v8*)&V[cur][vr][vc + u * 8] = rv[u];
        }
        __syncthreads();

        // ---- prefetch chunk ct+1 into registers (overlaps MFMA below) ----
        if (ct + 1 < SS / 64) {
            const int kn = kc + 64;
            ra0 = *(const float4*)&A[rawRow + kn + pc];
            ra1 = *(const float4*)&A[rawRow + kn + pc + 4];
            #pragma unroll
            for (int u = 0; u < 4; u++)
                rv[u] = *(const u16v8*)&Bv[vRow + kn + vc + u * 8];
        }

        // ---- MFMA on chunk ct: wave w owns C cols w*32..w*32+31 ----
        #pragma unroll
        for (int kk = 0; kk < 64; kk += 32) {
            u16v8 af[4], bf[2];
            #pragma unroll
            for (int i = 0; i < 4; i++)
                af[i] = *(const u16v8*)&P[cur][i * 16 + m][kk + qq * 8];
            #pragma unroll
            for (int j = 0; j < 2; j++)
                bf[j] = *(const u16v8*)&V[cur][w * 32 + j * 16 + m][kk + qq * 8];
            #pragma unroll
            for (int i = 0; i < 4; i++)
                #pragma unroll
                for (int j = 0; j < 2; j++)
                    acc[i][j] = mfma_bf16(af[i], bf[j], acc[i][j]);
        }
        cur ^= 1;
    }

    // ---- epilogue: write O ----
    #pragma unroll
    for (int i = 0; i < 4; i++) {
        #pragma unroll
        for (int j = 0; j < 2; j++) {
            #pragma unroll
            for (int rr = 0; rr < 4; rr++) {
                int row = rowBase + i * 16 + qq * 4 + rr;
                int col = w * 32 + j * 16 + m;
                out[((size_t)b * SS + row) * DD + col] = acc[i][j][rr];
            }
        }
    }
}

extern "C" void kernel_launch(void* const* d_in, const int* in_sizes, int n_in,
                              void* d_out, int out_size, void* d_ws, size_t ws_size,
                              hipStream_t stream)
{
    const float* query = (const float*)d_in[0];
    const float* key_  = (const float*)d_in[1];
    const float* value = (const float*)d_in[2];
    const float* Wq    = (const float*)d_in[3];
    const float* Wk    = (const float*)d_in[4];
    const float* Wv    = (const float*)d_in[5];

    float* out  = (float*)d_out;                          // [B,S,D]
    float* attn = out + (size_t)BB * SS * DD;             // [B,S,S]

    const size_t E = (size_t)BB * SS * DD;                // 4.19M elements
    unsigned short* qh = (unsigned short*)d_ws;
    unsigned short* ql = qh + E;
    unsigned short* kh = ql + E;
    unsigned short* kl = kh + E;
    unsigned short* vT = kl + E;                          // [B][D][S]
    float* pmax = (float*)(vT + E);                       // [32][NROW]
    float* psum = pmax + (size_t)32 * NROW;
    float* rmax = psum + (size_t)32 * NROW;               // [NROW]
    float* rinv = rmax + NROW;
    unsigned* gmax = (unsigned*)(rinv + NROW);

    // 1) projections via split-bf16 MFMA (+ gmax init)
    proj_mfma<<<dim3(DD / 128, NROW / 128, 3), 256, 0, stream>>>(
        query, key_, value, Wq, Wk, Wv, qh, ql, kh, kl, vT, gmax);
    // 2) raw scores + transposed softmax partials + global max
    scores_mfma<<<dim3(SS / 128, SS / 128, BB), 256, 0, stream>>>(
        qh, ql, kh, kl, attn, pmax, psum, gmax);
    // 3) combine partials -> per-row (max, 1/sum), exact biased-diag swap
    combine_kernel<<<dim3(NROW / 256), 256, 0, stream>>>(
        pmax, psum, attn, gmax, rmax, rinv);
    // 4) fused softmax (in-place weights) + AV
    av_fused2<<<dim3(SS / 64, BB), 512, 0, stream>>>(
        attn, vT, rmax, rinv, gmax, out);
}